// Round 17
// baseline (229.310 us; speedup 1.0000x reference)
//
#include <hip/hip_runtime.h>

typedef __bf16 bf16x8 __attribute__((ext_vector_type(8)));
typedef float f32x4 __attribute__((ext_vector_type(4)));
typedef unsigned short u16;
typedef u16 u16x4 __attribute__((ext_vector_type(4)));
typedef u16 u16x8 __attribute__((ext_vector_type(8)));

__device__ __forceinline__ u16 f2bf(float f) {
  unsigned u = __builtin_bit_cast(unsigned, f);
  unsigned r = (u + 0x7fffu + ((u >> 16) & 1u)) >> 16;  // RNE
  return (u16)r;
}

// async global->LDS, 16B per lane (dest = wave-uniform base + lane*16 in HW).
__device__ __forceinline__ void gld_lds16(const u16* g, u16* l) {
  __builtin_amdgcn_global_load_lds(
      (__attribute__((address_space(1))) void*)(g),
      (__attribute__((address_space(3))) void*)(l), 16, 0, 0);
}

// nontemporal 16B load (native clang vector type required by the builtin)
__device__ __forceinline__ f32x4 ntload4(const float* p) {
  return __builtin_nontemporal_load((const f32x4*)p);
}

// ---------------------------------------------------------------------------
// k_cvt: fp32 -> bf16 cast for K (y=0) and Q (y=1). Proven R16 (~60us, wall).
// ---------------------------------------------------------------------------
__global__ __launch_bounds__(256) void k_cvt(const float* __restrict__ K,
                                             const float* __restrict__ Q,
                                             u16* __restrict__ Kb,
                                             u16* __restrict__ Qb) {
  const float* src = blockIdx.y ? Q : K;
  u16* dst = blockIdx.y ? Qb : Kb;
  const size_t i = (size_t)blockIdx.x * 2048 + threadIdx.x * 8;
  f32x4 a = ntload4(src + i);
  f32x4 b = ntload4(src + i + 4);
  u16x8 h;
  h[0] = f2bf(a[0]); h[1] = f2bf(a[1]); h[2] = f2bf(a[2]); h[3] = f2bf(a[3]);
  h[4] = f2bf(b[0]); h[5] = f2bf(b[1]); h[6] = f2bf(b[2]); h[7] = f2bf(b[3]);
  *(u16x8*)(dst + i) = h;
}

// ---------------------------------------------------------------------------
// k_mix4: role-split, 34816B dyn-LDS -> 4 blocks/CU (32 waves, 2x R16's TLP).
//  simk role (bid%9==0, 512 roles): 128x128, BK=64, KDIV=2, SINGLE-buffered
//    (stage -> barrier -> compute -> barrier); cross-block TLP + vt streamers
//    cover the stage latency (R10 mechanism at double residency).
//  vt role (4096 roles): ONE 128d x 64s tile per 512-thread block.
// ---------------------------------------------------------------------------
__global__ __launch_bounds__(512) void k_mix4(const u16* __restrict__ Kb,
                                              const u16* __restrict__ Qb,
                                              float* __restrict__ Lp,
                                              const float* __restrict__ V,
                                              u16* __restrict__ Vt) {
  extern __shared__ char raw[];
  const int bid = blockIdx.x;
  const int t = threadIdx.x;

  if (bid % 9 == 0) {
    // ---------------- simk role: single-buffer 128x128, 32 KB ----------------
    u16* sA = (u16*)raw;              // [128*64] bf16 = 16 KB
    u16* sB = (u16*)(raw + 16384);    // [128*64] bf16 = 16 KB
    const int sid0 = bid / 9;                       // 0..511
    const int sid = (sid0 & 7) * 64 + (sid0 >> 3);  // bijective XCD swizzle
    const int n = sid >> 5;                         // PER_N = 32
    const int rem = sid & 31;
    const int kc = rem >> 4;
    const int r2 = rem & 15;
    const int cy = r2 >> 2, dx = r2 & 3;
    const int lane = t & 63, wid = t >> 6;
    const int wr = wid >> 2, wc = wid & 3;  // 2x4 waves, wave tile 64x32
    const float scale = 0.04419417382415922f;

    const u16* Ab = Kb + ((size_t)n * 512 + cy * 128) * 4096 + kc * 2048;
    const u16* Bb = Qb + ((size_t)n * 512 + dx * 128) * 4096 + kc * 2048;
    f32x4 acc[4][2] = {};
    const int srow0 = t >> 3;
    const int scol = ((t & 7) << 3) ^ ((srow0 & 7) << 3);

#define MIX_STAGE(k0)                                                           \
  {                                                                             \
    _Pragma("unroll") for (int q = 0; q < 2; ++q) {                             \
      const int row = q * 64 + srow0;                                           \
      gld_lds16(Ab + (size_t)row * 4096 + (k0) + scol,                          \
                sA + (q * 512 + (wid << 6)) * 8);                               \
      gld_lds16(Bb + (size_t)row * 4096 + (k0) + scol,                          \
                sB + (q * 512 + (wid << 6)) * 8);                               \
    }                                                                           \
  }
#define MIX_COMPUTE()                                                           \
  {                                                                             \
    _Pragma("unroll") for (int ki = 0; ki < 2; ++ki) {                          \
      bf16x8 a[4], b[2];                                                        \
      const int ce = ki * 32 + (lane >> 4) * 8;                                 \
      _Pragma("unroll") for (int mi = 0; mi < 4; ++mi) {                        \
        const int r = wr * 64 + mi * 16 + (lane & 15);                          \
        a[mi] = *(const bf16x8*)&sA[r * 64 + (ce ^ ((r & 7) << 3))];            \
      }                                                                         \
      _Pragma("unroll") for (int ni = 0; ni < 2; ++ni) {                        \
        const int r = wc * 32 + ni * 16 + (lane & 15);                          \
        b[ni] = *(const bf16x8*)&sB[r * 64 + (ce ^ ((r & 7) << 3))];            \
      }                                                                         \
      __builtin_amdgcn_s_setprio(1);                                            \
      _Pragma("unroll") for (int mi = 0; mi < 4; ++mi)                          \
        _Pragma("unroll") for (int ni = 0; ni < 2; ++ni)                        \
          acc[mi][ni] = __builtin_amdgcn_mfma_f32_16x16x32_bf16(                \
              a[mi], b[ni], acc[mi][ni], 0, 0, 0);                              \
      __builtin_amdgcn_s_setprio(0);                                            \
    }                                                                           \
  }

#pragma unroll 1
    for (int kt = 0; kt < 32; ++kt) {  // NSTEP=32 (KDIV=2)
      MIX_STAGE(kt << 6);
      __syncthreads();  // drains vmcnt: tile landed
      MIX_COMPUTE();
      __syncthreads();  // all reads done before next overwrite
    }

    float* Lb = Lp + ((size_t)kc * 16 + n) * 512 * 512;
    const int c0 = cy * 128, d0 = dx * 128;
#pragma unroll
    for (int mi = 0; mi < 4; ++mi)
#pragma unroll
      for (int ni = 0; ni < 2; ++ni) {
        int colo = d0 + wc * 32 + ni * 16 + (lane & 15);
#pragma unroll
        for (int j = 0; j < 4; ++j) {
          int rowo = c0 + wr * 64 + mi * 16 + ((lane >> 4) << 2) + j;
          Lb[(size_t)rowo * 512 + colo] = acc[mi][ni][j] * scale;
        }
      }
#undef MIX_STAGE
#undef MIX_COMPUTE
  } else {
    // ---------------- vt role: one 128d x 64s tile, 512 threads ----------------
    const int vid = bid - bid / 9 - 1;  // 0..4095
    const int n = vid >> 8;
    const int r = vid & 255;
    const int d0 = (r >> 6) * 128, s0 = (r & 63) * 64;
    float* lds = (float*)raw;  // [128][68] fp32 = 34816 B
    {
      const int r0 = t >> 4, c4 = (t & 15) << 2;  // 32 rows/pass, 64 cols
#pragma unroll
      for (int p = 0; p < 4; ++p) {
        const int dr = r0 + p * 32;
        f32x4 v = ntload4(V + ((size_t)n * 512 + d0 + dr) * 4096 + s0 + c4);
        const int sw = ((dr >> 3) & 7) << 2;
        *(f32x4*)(&lds[dr * 68 + (c4 ^ sw)]) = v;
      }
    }
    __syncthreads();
    {
      const int sr0 = t >> 4, dcol = (t & 15) << 3;  // 32 s-rows/pass
#pragma unroll
      for (int p2 = 0; p2 < 2; ++p2) {
        const int sr = sr0 + p2 * 32;
        u16x8 h;
#pragma unroll
        for (int j = 0; j < 8; ++j) {
          const int d = dcol + j;
          h[j] = f2bf(lds[d * 68 + (sr ^ (((d >> 3) & 7) << 2))]);
        }
        *(u16x8*)(Vt + ((size_t)n * 4096 + s0 + sr) * 512 + d0 + dcol) = h;
      }
    }
  }
}

// ---------------------------------------------------------------------------
// k_stats2<KDIV>: sum KDIV partials, softmax over c, write E bf16. Proven R16.
// ---------------------------------------------------------------------------
template <int KDIV>
__global__ __launch_bounds__(512) void k_stats2(const float* __restrict__ Lp,
                                                u16* __restrict__ E) {
  __shared__ f32x4 redm[16][32];
  __shared__ f32x4 reds[16][32];
  const int n = blockIdx.y;
  const int tx = threadIdx.x & 31, ty = threadIdx.x >> 5;  // ty 0..15
  const int d0 = blockIdx.x * 128 + tx * 4;
  const size_t CH = (size_t)16 * 512 * 512;
  const float* B = Lp + (size_t)n * 512 * 512 + d0;

  f32x4 m = {-3.0e38f, -3.0e38f, -3.0e38f, -3.0e38f};
  f32x4 s = {0.f, 0.f, 0.f, 0.f};
  for (int c = ty; c < 512; c += 16) {
    f32x4 v = *(const f32x4*)(B + (size_t)c * 512);
#pragma unroll
    for (int q = 1; q < KDIV; ++q) v += *(const f32x4*)(B + q * CH + (size_t)c * 512);
#pragma unroll
    for (int j = 0; j < 4; ++j) {
      float nm = fmaxf(m[j], v[j]);
      s[j] = s[j] * __expf(m[j] - nm) + __expf(v[j] - nm);
      m[j] = nm;
    }
  }
  redm[ty][tx] = m;
  reds[ty][tx] = s;
  __syncthreads();
  f32x4 M = redm[0][tx], S;
#pragma unroll
  for (int q = 1; q < 16; ++q)
#pragma unroll
    for (int j = 0; j < 4; ++j) M[j] = fmaxf(M[j], redm[q][tx][j]);
#pragma unroll
  for (int j = 0; j < 4; ++j) S[j] = 0.f;
#pragma unroll
  for (int q = 0; q < 16; ++q)
#pragma unroll
    for (int j = 0; j < 4; ++j) S[j] += reds[q][tx][j] * __expf(redm[q][tx][j] - M[j]);
  f32x4 si;
#pragma unroll
  for (int j = 0; j < 4; ++j) si[j] = 1.0f / S[j];

  u16* Eb = E + (size_t)n * 512 * 512 + d0;
  for (int c = ty; c < 512; c += 16) {
    f32x4 v = *(const f32x4*)(B + (size_t)c * 512);
#pragma unroll
    for (int q = 1; q < KDIV; ++q) v += *(const f32x4*)(B + q * CH + (size_t)c * 512);
    u16x4 h;
#pragma unroll
    for (int j = 0; j < 4; ++j) h[j] = f2bf(__expf(v[j] - M[j]) * si[j]);
    *(u16x4*)(Eb + (size_t)c * 512) = h;
  }
}

// ---------------------------------------------------------------------------
// Fallback serial path kernels (proven R8/R12): k_simk, k_vt.
// ---------------------------------------------------------------------------
template <int KDIV>
__global__ __launch_bounds__(512) void k_simk(const u16* __restrict__ Kb,
                                              const u16* __restrict__ Qb,
                                              float* __restrict__ Lp) {
  __shared__ u16 sA[2][128 * 64];
  __shared__ u16 sB[2][128 * 64];
  constexpr int NB = 256 * KDIV;
  const int bid = blockIdx.x;
  const int sid = (bid & 7) * (NB / 8) + (bid >> 3);
  constexpr int PER_N = 16 * KDIV;
  const int n = sid / PER_N;
  const int rem = sid % PER_N;
  const int kc = rem >> 4;
  const int r2 = rem & 15;
  const int cy = r2 >> 2, dx = r2 & 3;
  const int t = threadIdx.x, lane = t & 63, wid = t >> 6;
  const int wr = wid >> 2, wc = wid & 3;
  const float scale = 0.04419417382415922f;

  const u16* Ab = Kb + ((size_t)n * 512 + cy * 128) * 4096 + kc * (4096 / KDIV);
  const u16* Bb = Qb + ((size_t)n * 512 + dx * 128) * 4096 + kc * (4096 / KDIV);
  f32x4 acc[4][2] = {};
  const int srow0 = t >> 3;
  const int scol = ((t & 7) << 3) ^ ((srow0 & 7) << 3);

#define SIM_STAGE(buf, k0)                                                      \
  {                                                                             \
    _Pragma("unroll") for (int q = 0; q < 2; ++q) {                             \
      const int row = q * 64 + srow0;                                           \
      gld_lds16(Ab + (size_t)row * 4096 + (k0) + scol,                          \
                &sA[buf][(q * 512 + (wid << 6)) * 8]);                          \
      gld_lds16(Bb + (size_t)row * 4096 + (k0) + scol,                          \
                &sB[buf][(q * 512 + (wid << 6)) * 8]);                          \
    }                                                                           \
  }
#define SIM_COMPUTE(buf)                                                        \
  {                                                                             \
    _Pragma("unroll") for (int ki = 0; ki < 2; ++ki) {                          \
      bf16x8 a[4], b[2];                                                        \
      const int ce = ki * 32 + (lane >> 4) * 8;                                 \
      _Pragma("unroll") for (int mi = 0; mi < 4; ++mi) {                        \
        const int r = wr * 64 + mi * 16 + (lane & 15);                          \
        a[mi] = *(const bf16x8*)&sA[buf][r * 64 + (ce ^ ((r & 7) << 3))];       \
      }                                                                         \
      _Pragma("unroll") for (int ni = 0; ni < 2; ++ni) {                        \
        const int r = wc * 32 + ni * 16 + (lane & 15);                          \
        b[ni] = *(const bf16x8*)&sB[buf][r * 64 + (ce ^ ((r & 7) << 3))];       \
      }                                                                         \
      _Pragma("unroll") for (int mi = 0; mi < 4; ++mi)                          \
        _Pragma("unroll") for (int ni = 0; ni < 2; ++ni)                        \
          acc[mi][ni] = __builtin_amdgcn_mfma_f32_16x16x32_bf16(                \
              a[mi], b[ni], acc[mi][ni], 0, 0, 0);                              \
    }                                                                           \
  }

  constexpr int NSTEP = 64 / KDIV;
  SIM_STAGE(0, 0);
  __syncthreads();
  int cur = 0;
  for (int kt = 0; kt < NSTEP - 1; ++kt) {
    SIM_STAGE(cur ^ 1, (kt + 1) << 6);
    SIM_COMPUTE(cur);
    __syncthreads();
    cur ^= 1;
  }
  SIM_COMPUTE(cur);

  float* Lb = Lp + ((size_t)kc * 16 + n) * 512 * 512;
  const int c0 = cy * 128, d0 = dx * 128;
#pragma unroll
  for (int mi = 0; mi < 4; ++mi)
#pragma unroll
    for (int ni = 0; ni < 2; ++ni) {
      int colo = d0 + wc * 32 + ni * 16 + (lane & 15);
#pragma unroll
      for (int j = 0; j < 4; ++j) {
        int rowo = c0 + wr * 64 + mi * 16 + ((lane >> 4) << 2) + j;
        Lb[(size_t)rowo * 512 + colo] = acc[mi][ni][j] * scale;
      }
    }
#undef SIM_STAGE
#undef SIM_COMPUTE
}

__global__ __launch_bounds__(256) void k_vt(const float* __restrict__ V,
                                            u16* __restrict__ Vt) {
  __shared__ float lds[128 * 68];
  const int n = blockIdx.z, d0 = blockIdx.y * 128, s0 = blockIdx.x * 64;
  const int t = threadIdx.x;
  {
    const int r0 = t >> 4, c4 = (t & 15) << 2;
#pragma unroll
    for (int p = 0; p < 8; ++p) {
      const int dr = r0 + p * 16;
      f32x4 v = ntload4(V + ((size_t)n * 512 + d0 + dr) * 4096 + s0 + c4);
      const int sw = ((dr >> 3) & 7) << 2;
      *(f32x4*)(&lds[dr * 68 + (c4 ^ sw)]) = v;
    }
  }
  __syncthreads();
  {
    const int sr0 = t >> 4, dcol = (t & 15) << 3;
#pragma unroll
    for (int p2 = 0; p2 < 4; ++p2) {
      const int sr = sr0 + p2 * 16;
      u16x8 h;
#pragma unroll
      for (int j = 0; j < 8; ++j) {
        const int d = dcol + j;
        h[j] = f2bf(lds[d * 68 + (sr ^ (((d >> 3) & 7) << 2))]);
      }
      *(u16x8*)(Vt + ((size_t)n * 4096 + s0 + sr) * 512 + d0 + dcol) = h;
    }
  }
}

// ---------------------------------------------------------------------------
// k_ctx3: out[n,c,s] = sum_d E[n,c,d]*Vt[n,s,d]. Proven R12 (~50us).
// ---------------------------------------------------------------------------
__global__ __launch_bounds__(512) void k_ctx3(const u16* __restrict__ E,
                                              const u16* __restrict__ Vt,
                                              float* __restrict__ O) {
  __shared__ u16 sA[2][128 * 64];
  __shared__ u16 sB[2][128 * 64];
  const int bid = blockIdx.x;
  const int sid = (bid & 7) * 256 + (bid >> 3);  // 2048 % 8 == 0, bijective
  const int n = sid >> 7;
  const int rem = sid & 127;
  const int cy = rem >> 5, sx = rem & 31;
  const int t = threadIdx.x, lane = t & 63, wid = t >> 6;
  const int wr = wid >> 2, wc = wid & 3;  // 2x4 waves, wave tile 64x32

  const u16* Ab = E + ((size_t)n * 512 + cy * 128) * 512;
  const u16* Bb = Vt + ((size_t)n * 4096 + sx * 128) * 512;
  const int srow0 = t >> 3;
  const int scol = ((t & 7) << 3) ^ ((srow0 & 7) << 3);
  f32x4 acc[4][2] = {};

#define CTX_STAGE(buf, kd)                                                      \
  {                                                                             \
    _Pragma("unroll") for (int q = 0; q < 2; ++q) {                             \
      const int row = q * 64 + srow0;                                           \
      gld_lds16(Ab + (size_t)row * 512 + (kd) + scol,                           \
                &sA[buf][(q * 512 + (wid << 6)) * 8]);                          \
      gld_lds16(Bb + (size_t)row * 512 + (kd) + scol,                           \
                &sB[buf][(q * 512 + (wid << 6)) * 8]);                          \
    }                                                                           \
  }
#define CTX_COMPUTE(buf)                                                        \
  {                                                                             \
    _Pragma("unroll") for (int ki = 0; ki < 2; ++ki) {                          \
      bf16x8 a[4], b[2];                                                        \
      const int ce = ki * 32 + (lane >> 4) * 8;                                 \
      _Pragma("unroll") for (int mi = 0; mi < 4; ++mi) {                        \
        const int r = wr * 64 + mi * 16 + (lane & 15);                          \
        a[mi] = *(const bf16x8*)&sA[buf][r * 64 + (ce ^ ((r & 7) << 3))];       \
      }                                                                         \
      _Pragma("unroll") for (int ni = 0; ni < 2; ++ni) {                        \
        const int r = wc * 32 + ni * 16 + (lane & 15);                          \
        b[ni] = *(const bf16x8*)&sB[buf][r * 64 + (ce ^ ((r & 7) << 3))];       \
      }                                                                         \
      _Pragma("unroll") for (int mi = 0; mi < 4; ++mi)                          \
        _Pragma("unroll") for (int ni = 0; ni < 2; ++ni)                        \
          acc[mi][ni] = __builtin_amdgcn_mfma_f32_16x16x32_bf16(                \
              a[mi], b[ni], acc[mi][ni], 0, 0, 0);                              \
    }                                                                           \
  }

  CTX_STAGE(0, 0);
  __syncthreads();
  int cur = 0;
  for (int kt = 0; kt < 7; ++kt) {  // 8 K-steps (K=512, BK=64)
    CTX_STAGE(cur ^ 1, (kt + 1) << 6);
    CTX_COMPUTE(cur);
    __syncthreads();
    cur ^= 1;
  }
  CTX_COMPUTE(cur);

  float* Ob = O + ((size_t)n * 512 + cy * 128) * 4096 + sx * 128;
#pragma unroll
  for (int mi = 0; mi < 4; ++mi)
#pragma unroll
    for (int ni = 0; ni < 2; ++ni) {
      int colo = wc * 32 + ni * 16 + (lane & 15);
#pragma unroll
      for (int j = 0; j < 4; ++j) {
        int rowo = wr * 64 + mi * 16 + ((lane >> 4) << 2) + j;
        __builtin_nontemporal_store(acc[mi][ni][j], &Ob[(size_t)rowo * 4096 + colo]);
      }
    }
#undef CTX_STAGE
#undef CTX_COMPUTE
}

extern "C" void kernel_launch(void* const* d_in, const int* in_sizes, int n_in,
                              void* d_out, int out_size, void* d_ws, size_t ws_size,
                              hipStream_t stream) {
  const float* Kp = (const float*)d_in[0];  // key
  const float* Vp = (const float*)d_in[1];  // value
  const float* Qp = (const float*)d_in[2];  // query
  float* Op = (float*)d_out;
  char* ws = (char*)d_ws;
  const size_t MB = 1024 * 1024;

  if (ws_size >= 192 * MB) {
    // Primary: Kb@0(64), Qb@64(64), Vt@128(64); E aliases Qb (dead after mix).
    // Lp (2x16 MiB fp32) in d_out.
    u16* Kb = (u16*)ws;
    u16* Qb = (u16*)(ws + 64 * MB);
    u16* Vt = (u16*)(ws + 128 * MB);
    u16* E  = (u16*)(ws + 64 * MB);
    float* Lp = Op;

    k_cvt<<<dim3(16384, 2), 256, 0, stream>>>(Kp, Qp, Kb, Qb);
    k_mix4<<<4608, 512, 34816, stream>>>(Kb, Qb, Lp, Vp, Vt);
    k_stats2<2><<<dim3(4, 16), 512, 0, stream>>>(Lp, E);
    k_ctx3<<<2048, 512, 0, stream>>>(E, Vt, Op);
  } else if (ws_size >= 128 * MB) {
    // Serial fallback (proven R8/R12).
    u16* Kb = (u16*)ws;
    u16* Qb = (u16*)(ws + 64 * MB);
    u16* Vt = (u16*)ws;
    u16* E  = (u16*)(ws + 64 * MB);
    float* Lp = Op;

    k_cvt<<<dim3(16384, 2), 256, 0, stream>>>(Kp, Qp, Kb, Qb);
    k_simk<2><<<512, 512, 0, stream>>>(Kb, Qb, Lp);
    k_stats2<2><<<dim3(4, 16), 512, 0, stream>>>(Lp, E);
    k_vt<<<dim3(64, 4, 16), 256, 0, stream>>>(Vp, Vt);
    k_ctx3<<<2048, 512, 0, stream>>>(E, Vt, Op);
  }
}

// Round 18
// 220.733 us; speedup vs baseline: 1.0389x; 1.0389x over previous
//
#include <hip/hip_runtime.h>

typedef __bf16 bf16x8 __attribute__((ext_vector_type(8)));
typedef float f32x4 __attribute__((ext_vector_type(4)));
typedef unsigned short u16;
typedef u16 u16x4 __attribute__((ext_vector_type(4)));
typedef u16 u16x8 __attribute__((ext_vector_type(8)));

__device__ __forceinline__ u16 f2bf(float f) {
  unsigned u = __builtin_bit_cast(unsigned, f);
  unsigned r = (u + 0x7fffu + ((u >> 16) & 1u)) >> 16;  // RNE
  return (u16)r;
}

// async global->LDS, 16B per lane (dest = wave-uniform base + lane*16 in HW).
__device__ __forceinline__ void gld_lds16(const u16* g, u16* l) {
  __builtin_amdgcn_global_load_lds(
      (__attribute__((address_space(1))) void*)(g),
      (__attribute__((address_space(3))) void*)(l), 16, 0, 0);
}

// nontemporal 16B load (native clang vector type required by the builtin)
__device__ __forceinline__ f32x4 ntload4(const float* p) {
  return __builtin_nontemporal_load((const f32x4*)p);
}

// ---------------------------------------------------------------------------
// k_cvt: fp32 -> bf16 cast for K (y=0) and Q (y=1). Proven R16 (~60us, wall).
// ---------------------------------------------------------------------------
__global__ __launch_bounds__(256) void k_cvt(const float* __restrict__ K,
                                             const float* __restrict__ Q,
                                             u16* __restrict__ Kb,
                                             u16* __restrict__ Qb) {
  const float* src = blockIdx.y ? Q : K;
  u16* dst = blockIdx.y ? Qb : Kb;
  const size_t i = (size_t)blockIdx.x * 2048 + threadIdx.x * 8;
  f32x4 a = ntload4(src + i);
  f32x4 b = ntload4(src + i + 4);
  u16x8 h;
  h[0] = f2bf(a[0]); h[1] = f2bf(a[1]); h[2] = f2bf(a[2]); h[3] = f2bf(a[3]);
  h[4] = f2bf(b[0]); h[5] = f2bf(b[1]); h[6] = f2bf(b[2]); h[7] = f2bf(b[3]);
  *(u16x8*)(dst + i) = h;
}

// ---------------------------------------------------------------------------
// k_mix: role-split kernel = simk<2> (bid%5==0, 512 roles) || vt (2048 tiny
// roles, 2 tiles each). Proven 78us across R10/R12/R16 (invariant under
// dbuf/sbuf and occupancy changes -> at its multi-resource equilibrium).
// ---------------------------------------------------------------------------
__global__ __launch_bounds__(512) void k_mix(const u16* __restrict__ Kb,
                                             const u16* __restrict__ Qb,
                                             float* __restrict__ Lp,
                                             const float* __restrict__ V,
                                             u16* __restrict__ Vt) {
  extern __shared__ char raw[];
  const int bid = blockIdx.x;
  const int t = threadIdx.x;

  if (bid % 5 == 0) {
    // ---------------- simk<2> role ----------------
    u16* sA = (u16*)raw;              // [2][8192]
    u16* sB = (u16*)(raw + 32768);    // [2][8192]
    const int sid0 = bid / 5;                       // 0..511
    const int sid = (sid0 & 7) * 64 + (sid0 >> 3);  // bijective XCD swizzle
    const int n = sid >> 5;                         // PER_N = 32
    const int rem = sid & 31;
    const int kc = rem >> 4;
    const int r2 = rem & 15;
    const int cy = r2 >> 2, dx = r2 & 3;
    const int lane = t & 63, wid = t >> 6;
    const int wr = wid >> 2, wc = wid & 3;
    const float scale = 0.04419417382415922f;

    const u16* Ab = Kb + ((size_t)n * 512 + cy * 128) * 4096 + kc * 2048;
    const u16* Bb = Qb + ((size_t)n * 512 + dx * 128) * 4096 + kc * 2048;
    f32x4 acc[4][2] = {};
    const int srow0 = t >> 3;
    const int scol = ((t & 7) << 3) ^ ((srow0 & 7) << 3);

#define MIX_STAGE(buf, k0)                                                      \
  {                                                                             \
    _Pragma("unroll") for (int q = 0; q < 2; ++q) {                             \
      const int row = q * 64 + srow0;                                           \
      gld_lds16(Ab + (size_t)row * 4096 + (k0) + scol,                          \
                sA + (buf) * 8192 + (q * 512 + (wid << 6)) * 8);                \
      gld_lds16(Bb + (size_t)row * 4096 + (k0) + scol,                          \
                sB + (buf) * 8192 + (q * 512 + (wid << 6)) * 8);                \
    }                                                                           \
  }
#define MIX_COMPUTE(buf)                                                        \
  {                                                                             \
    _Pragma("unroll") for (int ki = 0; ki < 2; ++ki) {                          \
      bf16x8 a[4], b[2];                                                        \
      const int ce = ki * 32 + (lane >> 4) * 8;                                 \
      _Pragma("unroll") for (int mi = 0; mi < 4; ++mi) {                        \
        const int r = wr * 64 + mi * 16 + (lane & 15);                          \
        a[mi] = *(const bf16x8*)&sA[(buf) * 8192 + r * 64 + (ce ^ ((r & 7) << 3))]; \
      }                                                                         \
      _Pragma("unroll") for (int ni = 0; ni < 2; ++ni) {                        \
        const int r = wc * 32 + ni * 16 + (lane & 15);                          \
        b[ni] = *(const bf16x8*)&sB[(buf) * 8192 + r * 64 + (ce ^ ((r & 7) << 3))]; \
      }                                                                         \
      __builtin_amdgcn_s_setprio(1);                                            \
      _Pragma("unroll") for (int mi = 0; mi < 4; ++mi)                          \
        _Pragma("unroll") for (int ni = 0; ni < 2; ++ni)                        \
          acc[mi][ni] = __builtin_amdgcn_mfma_f32_16x16x32_bf16(                \
              a[mi], b[ni], acc[mi][ni], 0, 0, 0);                              \
      __builtin_amdgcn_s_setprio(0);                                            \
    }                                                                           \
  }

    MIX_STAGE(0, 0);
    __syncthreads();
    int cur = 0;
    for (int kt = 0; kt < 31; ++kt) {  // NSTEP=32 (KDIV=2)
      MIX_STAGE(cur ^ 1, (kt + 1) << 6);
      MIX_COMPUTE(cur);
      __syncthreads();
      cur ^= 1;
    }
    MIX_COMPUTE(cur);

    float* Lb = Lp + ((size_t)kc * 16 + n) * 512 * 512;
    const int c0 = cy * 128, d0 = dx * 128;
#pragma unroll
    for (int mi = 0; mi < 4; ++mi)
#pragma unroll
      for (int ni = 0; ni < 2; ++ni) {
        int colo = d0 + wc * 32 + ni * 16 + (lane & 15);
#pragma unroll
        for (int j = 0; j < 4; ++j) {
          int rowo = c0 + wr * 64 + mi * 16 + ((lane >> 4) << 2) + j;
          Lb[(size_t)rowo * 512 + colo] = acc[mi][ni][j] * scale;
        }
      }
#undef MIX_STAGE
#undef MIX_COMPUTE
  } else {
    // ---------------- vt role (2 tiles of 128d x 64s per block) ----------------
    const int vid = bid - bid / 5 - 1;  // 0..2047
    const int sub = t >> 8, tt = t & 255;
    const int tile = vid * 2 + sub;     // 0..4095
    const int n = tile >> 8;
    const int r = tile & 255;
    const int d0 = (r >> 6) * 128, s0 = (r & 63) * 64;
    float* lds = (float*)(raw + sub * 34816);  // [128][68] fp32
    {
      const int r0 = tt >> 4, c4 = (tt & 15) << 2;
#pragma unroll
      for (int p = 0; p < 8; ++p) {
        const int dr = r0 + p * 16;
        f32x4 v = ntload4(V + ((size_t)n * 512 + d0 + dr) * 4096 + s0 + c4);
        const int sw = ((dr >> 3) & 7) << 2;
        *(f32x4*)(&lds[dr * 68 + (c4 ^ sw)]) = v;
      }
    }
    __syncthreads();
    {
      const int sr0 = tt >> 4, dcol = (tt & 15) << 3;
#pragma unroll
      for (int p2 = 0; p2 < 4; ++p2) {
        const int sr = sr0 + p2 * 16;
        u16x8 h;
#pragma unroll
        for (int j = 0; j < 8; ++j) {
          const int d = dcol + j;
          h[j] = f2bf(lds[d * 68 + (sr ^ (((d >> 3) & 7) << 2))]);
        }
        *(u16x8*)(Vt + ((size_t)n * 4096 + s0 + sr) * 512 + d0 + dcol) = h;
      }
    }
  }
}

// ---------------------------------------------------------------------------
// k_stats2<KDIV>: sum KDIV partials, softmax over c, write E bf16. Proven R16.
// ---------------------------------------------------------------------------
template <int KDIV>
__global__ __launch_bounds__(512) void k_stats2(const float* __restrict__ Lp,
                                                u16* __restrict__ E) {
  __shared__ f32x4 redm[16][32];
  __shared__ f32x4 reds[16][32];
  const int n = blockIdx.y;
  const int tx = threadIdx.x & 31, ty = threadIdx.x >> 5;  // ty 0..15
  const int d0 = blockIdx.x * 128 + tx * 4;
  const size_t CH = (size_t)16 * 512 * 512;
  const float* B = Lp + (size_t)n * 512 * 512 + d0;

  f32x4 m = {-3.0e38f, -3.0e38f, -3.0e38f, -3.0e38f};
  f32x4 s = {0.f, 0.f, 0.f, 0.f};
  for (int c = ty; c < 512; c += 16) {
    f32x4 v = *(const f32x4*)(B + (size_t)c * 512);
#pragma unroll
    for (int q = 1; q < KDIV; ++q) v += *(const f32x4*)(B + q * CH + (size_t)c * 512);
#pragma unroll
    for (int j = 0; j < 4; ++j) {
      float nm = fmaxf(m[j], v[j]);
      s[j] = s[j] * __expf(m[j] - nm) + __expf(v[j] - nm);
      m[j] = nm;
    }
  }
  redm[ty][tx] = m;
  reds[ty][tx] = s;
  __syncthreads();
  f32x4 M = redm[0][tx], S;
#pragma unroll
  for (int q = 1; q < 16; ++q)
#pragma unroll
    for (int j = 0; j < 4; ++j) M[j] = fmaxf(M[j], redm[q][tx][j]);
#pragma unroll
  for (int j = 0; j < 4; ++j) S[j] = 0.f;
#pragma unroll
  for (int q = 0; q < 16; ++q)
#pragma unroll
    for (int j = 0; j < 4; ++j) S[j] += reds[q][tx][j] * __expf(redm[q][tx][j] - M[j]);
  f32x4 si;
#pragma unroll
  for (int j = 0; j < 4; ++j) si[j] = 1.0f / S[j];

  u16* Eb = E + (size_t)n * 512 * 512 + d0;
  for (int c = ty; c < 512; c += 16) {
    f32x4 v = *(const f32x4*)(B + (size_t)c * 512);
#pragma unroll
    for (int q = 1; q < KDIV; ++q) v += *(const f32x4*)(B + q * CH + (size_t)c * 512);
    u16x4 h;
#pragma unroll
    for (int j = 0; j < 4; ++j) h[j] = f2bf(__expf(v[j] - M[j]) * si[j]);
    *(u16x4*)(Eb + (size_t)c * 512) = h;
  }
}

// ---------------------------------------------------------------------------
// Fallback serial path kernels (proven R8/R12): k_simk, k_vt.
// ---------------------------------------------------------------------------
template <int KDIV>
__global__ __launch_bounds__(512) void k_simk(const u16* __restrict__ Kb,
                                              const u16* __restrict__ Qb,
                                              float* __restrict__ Lp) {
  __shared__ u16 sA[2][128 * 64];
  __shared__ u16 sB[2][128 * 64];
  constexpr int NB = 256 * KDIV;
  const int bid = blockIdx.x;
  const int sid = (bid & 7) * (NB / 8) + (bid >> 3);
  constexpr int PER_N = 16 * KDIV;
  const int n = sid / PER_N;
  const int rem = sid % PER_N;
  const int kc = rem >> 4;
  const int r2 = rem & 15;
  const int cy = r2 >> 2, dx = r2 & 3;
  const int t = threadIdx.x, lane = t & 63, wid = t >> 6;
  const int wr = wid >> 2, wc = wid & 3;
  const float scale = 0.04419417382415922f;

  const u16* Ab = Kb + ((size_t)n * 512 + cy * 128) * 4096 + kc * (4096 / KDIV);
  const u16* Bb = Qb + ((size_t)n * 512 + dx * 128) * 4096 + kc * (4096 / KDIV);
  f32x4 acc[4][2] = {};
  const int srow0 = t >> 3;
  const int scol = ((t & 7) << 3) ^ ((srow0 & 7) << 3);

#define SIM_STAGE(buf, k0)                                                      \
  {                                                                             \
    _Pragma("unroll") for (int q = 0; q < 2; ++q) {                             \
      const int row = q * 64 + srow0;                                           \
      gld_lds16(Ab + (size_t)row * 4096 + (k0) + scol,                          \
                &sA[buf][(q * 512 + (wid << 6)) * 8]);                          \
      gld_lds16(Bb + (size_t)row * 4096 + (k0) + scol,                          \
                &sB[buf][(q * 512 + (wid << 6)) * 8]);                          \
    }                                                                           \
  }
#define SIM_COMPUTE(buf)                                                        \
  {                                                                             \
    _Pragma("unroll") for (int ki = 0; ki < 2; ++ki) {                          \
      bf16x8 a[4], b[2];                                                        \
      const int ce = ki * 32 + (lane >> 4) * 8;                                 \
      _Pragma("unroll") for (int mi = 0; mi < 4; ++mi) {                        \
        const int r = wr * 64 + mi * 16 + (lane & 15);                          \
        a[mi] = *(const bf16x8*)&sA[buf][r * 64 + (ce ^ ((r & 7) << 3))];       \
      }                                                                         \
      _Pragma("unroll") for (int ni = 0; ni < 2; ++ni) {                        \
        const int r = wc * 32 + ni * 16 + (lane & 15);                          \
        b[ni] = *(const bf16x8*)&sB[buf][r * 64 + (ce ^ ((r & 7) << 3))];       \
      }                                                                         \
      _Pragma("unroll") for (int mi = 0; mi < 4; ++mi)                          \
        _Pragma("unroll") for (int ni = 0; ni < 2; ++ni)                        \
          acc[mi][ni] = __builtin_amdgcn_mfma_f32_16x16x32_bf16(                \
              a[mi], b[ni], acc[mi][ni], 0, 0, 0);                              \
    }                                                                           \
  }

  constexpr int NSTEP = 64 / KDIV;
  SIM_STAGE(0, 0);
  __syncthreads();
  int cur = 0;
  for (int kt = 0; kt < NSTEP - 1; ++kt) {
    SIM_STAGE(cur ^ 1, (kt + 1) << 6);
    SIM_COMPUTE(cur);
    __syncthreads();
    cur ^= 1;
  }
  SIM_COMPUTE(cur);

  float* Lb = Lp + ((size_t)kc * 16 + n) * 512 * 512;
  const int c0 = cy * 128, d0 = dx * 128;
#pragma unroll
  for (int mi = 0; mi < 4; ++mi)
#pragma unroll
    for (int ni = 0; ni < 2; ++ni) {
      int colo = d0 + wc * 32 + ni * 16 + (lane & 15);
#pragma unroll
      for (int j = 0; j < 4; ++j) {
        int rowo = c0 + wr * 64 + mi * 16 + ((lane >> 4) << 2) + j;
        Lb[(size_t)rowo * 512 + colo] = acc[mi][ni][j] * scale;
      }
    }
#undef SIM_STAGE
#undef SIM_COMPUTE
}

__global__ __launch_bounds__(256) void k_vt(const float* __restrict__ V,
                                            u16* __restrict__ Vt) {
  __shared__ float lds[128 * 68];
  const int n = blockIdx.z, d0 = blockIdx.y * 128, s0 = blockIdx.x * 64;
  const int t = threadIdx.x;
  {
    const int r0 = t >> 4, c4 = (t & 15) << 2;
#pragma unroll
    for (int p = 0; p < 8; ++p) {
      const int dr = r0 + p * 16;
      f32x4 v = ntload4(V + ((size_t)n * 512 + d0 + dr) * 4096 + s0 + c4);
      const int sw = ((dr >> 3) & 7) << 2;
      *(f32x4*)(&lds[dr * 68 + (c4 ^ sw)]) = v;
    }
  }
  __syncthreads();
  {
    const int sr0 = t >> 4, dcol = (t & 15) << 3;
#pragma unroll
    for (int p2 = 0; p2 < 4; ++p2) {
      const int sr = sr0 + p2 * 16;
      u16x8 h;
#pragma unroll
      for (int j = 0; j < 8; ++j) {
        const int d = dcol + j;
        h[j] = f2bf(lds[d * 68 + (sr ^ (((d >> 3) & 7) << 2))]);
      }
      *(u16x8*)(Vt + ((size_t)n * 4096 + s0 + sr) * 512 + d0 + dcol) = h;
    }
  }
}

// ---------------------------------------------------------------------------
// k_ctx4: out[n,c,s] = sum_d E[n,c,d]*Vt[n,s,d]
// R12 K-loop (128x128 tile, BK=64, dbuf gld_lds) + NEW LDS-transpose epilogue:
// acc -> fp32 LDS tile (2-way banks via XOR) -> 16B nt vector stores
// (1KB/wave full-line writes vs 4 half-line segments before).
// LDS union: dbuf (64KB) reused as fp32[128][128] (64KB) post-loop.
// ---------------------------------------------------------------------------
__global__ __launch_bounds__(512) void k_ctx4(const u16* __restrict__ E,
                                              const u16* __restrict__ Vt,
                                              float* __restrict__ O) {
  __shared__ char lbuf[65536];
  u16* sA = (u16*)lbuf;               // [2][8192] u16 (K-loop)
  u16* sB = (u16*)(lbuf + 32768);     // [2][8192]
  float* ldsf = (float*)lbuf;         // [128*128] fp32 (epilogue)
  const int bid = blockIdx.x;
  const int sid = (bid & 7) * 256 + (bid >> 3);  // 2048 % 8 == 0, bijective
  const int n = sid >> 7;
  const int rem = sid & 127;
  const int cy = rem >> 5, sx = rem & 31;
  const int t = threadIdx.x, lane = t & 63, wid = t >> 6;
  const int wr = wid >> 2, wc = wid & 3;  // 2x4 waves, wave tile 64x32

  const u16* Ab = E + ((size_t)n * 512 + cy * 128) * 512;
  const u16* Bb = Vt + ((size_t)n * 4096 + sx * 128) * 512;
  const int srow0 = t >> 3;
  const int scol = ((t & 7) << 3) ^ ((srow0 & 7) << 3);
  f32x4 acc[4][2] = {};

#define CTX_STAGE(buf, kd)                                                      \
  {                                                                             \
    _Pragma("unroll") for (int q = 0; q < 2; ++q) {                             \
      const int row = q * 64 + srow0;                                           \
      gld_lds16(Ab + (size_t)row * 512 + (kd) + scol,                           \
                sA + (buf) * 8192 + (q * 512 + (wid << 6)) * 8);                \
      gld_lds16(Bb + (size_t)row * 512 + (kd) + scol,                           \
                sB + (buf) * 8192 + (q * 512 + (wid << 6)) * 8);                \
    }                                                                           \
  }
#define CTX_COMPUTE(buf)                                                        \
  {                                                                             \
    _Pragma("unroll") for (int ki = 0; ki < 2; ++ki) {                          \
      bf16x8 a[4], b[2];                                                        \
      const int ce = ki * 32 + (lane >> 4) * 8;                                 \
      _Pragma("unroll") for (int mi = 0; mi < 4; ++mi) {                        \
        const int r = wr * 64 + mi * 16 + (lane & 15);                          \
        a[mi] = *(const bf16x8*)&sA[(buf) * 8192 + r * 64 + (ce ^ ((r & 7) << 3))]; \
      }                                                                         \
      _Pragma("unroll") for (int ni = 0; ni < 2; ++ni) {                        \
        const int r = wc * 32 + ni * 16 + (lane & 15);                          \
        b[ni] = *(const bf16x8*)&sB[(buf) * 8192 + r * 64 + (ce ^ ((r & 7) << 3))]; \
      }                                                                         \
      _Pragma("unroll") for (int mi = 0; mi < 4; ++mi)                          \
        _Pragma("unroll") for (int ni = 0; ni < 2; ++ni)                        \
          acc[mi][ni] = __builtin_amdgcn_mfma_f32_16x16x32_bf16(                \
              a[mi], b[ni], acc[mi][ni], 0, 0, 0);                              \
    }                                                                           \
  }

  CTX_STAGE(0, 0);
  __syncthreads();
  int cur = 0;
  for (int kt = 0; kt < 7; ++kt) {  // 8 K-steps (K=512, BK=64)
    CTX_STAGE(cur ^ 1, (kt + 1) << 6);
    CTX_COMPUTE(cur);
    __syncthreads();
    cur ^= 1;
  }
  CTX_COMPUTE(cur);
  __syncthreads();  // all LDS reads done before epilogue overwrites dbuf

  // ---- epilogue: acc -> fp32 LDS (XOR-swizzled), then 16B nt row stores ----
#pragma unroll
  for (int mi = 0; mi < 4; ++mi)
#pragma unroll
    for (int ni = 0; ni < 2; ++ni) {
      const int cl = wc * 32 + ni * 16 + (lane & 15);
#pragma unroll
      for (int j = 0; j < 4; ++j) {
        const int rl = wr * 64 + mi * 16 + ((lane >> 4) << 2) + j;
        ldsf[rl * 128 + (cl ^ (((rl >> 2) & 1) << 4))] = acc[mi][ni][j];
      }
    }
  __syncthreads();
  float* Ob = O + ((size_t)n * 512 + cy * 128) * 4096 + sx * 128;
#pragma unroll
  for (int p = 0; p < 8; ++p) {
    const int chunk = p * 512 + t;       // 0..4095
    const int row = chunk >> 5;          // 0..127
    const int c4 = (chunk & 31) << 2;    // 0..124
    f32x4 v = *(const f32x4*)&ldsf[row * 128 + (c4 ^ (((row >> 2) & 1) << 4))];
    __builtin_nontemporal_store(v, (f32x4*)(Ob + (size_t)row * 4096 + c4));
  }
#undef CTX_STAGE
#undef CTX_COMPUTE
}

extern "C" void kernel_launch(void* const* d_in, const int* in_sizes, int n_in,
                              void* d_out, int out_size, void* d_ws, size_t ws_size,
                              hipStream_t stream) {
  const float* Kp = (const float*)d_in[0];  // key
  const float* Vp = (const float*)d_in[1];  // value
  const float* Qp = (const float*)d_in[2];  // query
  float* Op = (float*)d_out;
  char* ws = (char*)d_ws;
  const size_t MB = 1024 * 1024;

  if (ws_size >= 192 * MB) {
    // Primary (R16 structure): Kb@0(64), Qb@64(64), Vt@128(64); E aliases Qb.
    // Lp (2x16 MiB fp32) in d_out.
    u16* Kb = (u16*)ws;
    u16* Qb = (u16*)(ws + 64 * MB);
    u16* Vt = (u16*)(ws + 128 * MB);
    u16* E  = (u16*)(ws + 64 * MB);
    float* Lp = Op;

    k_cvt<<<dim3(16384, 2), 256, 0, stream>>>(Kp, Qp, Kb, Qb);
    k_mix<<<2560, 512, 69632, stream>>>(Kb, Qb, Lp, Vp, Vt);
    k_stats2<2><<<dim3(4, 16), 512, 0, stream>>>(Lp, E);
    k_ctx4<<<2048, 512, 0, stream>>>(E, Vt, Op);
  } else if (ws_size >= 128 * MB) {
    // Serial fallback (proven R8/R12).
    u16* Kb = (u16*)ws;
    u16* Qb = (u16*)(ws + 64 * MB);
    u16* Vt = (u16*)ws;
    u16* E  = (u16*)(ws + 64 * MB);
    float* Lp = Op;

    k_cvt<<<dim3(16384, 2), 256, 0, stream>>>(Kp, Qp, Kb, Qb);
    k_simk<2><<<512, 512, 0, stream>>>(Kb, Qb, Lp);
    k_stats2<2><<<dim3(4, 16), 512, 0, stream>>>(Lp, E);
    k_vt<<<dim3(64, 4, 16), 256, 0, stream>>>(Vp, Vt);
    k_ctx4<<<2048, 512, 0, stream>>>(E, Vt, Op);
  }
}